// Round 1
// baseline (399.864 us; speedup 1.0000x reference)
//
#include <hip/hip_runtime.h>
#include <hip/hip_bf16.h>

typedef __attribute__((ext_vector_type(4))) float f32x4;
typedef __attribute__((ext_vector_type(8))) short bf16x8;

#define BM 128
#define BN 128
#define BK 64
#define KDIM 512
#define NT (KDIM / BK)   // 8 K-tiles

// fp32 -> packed 2x bf16 (RNE). Compiler emits v_cvt_pk_bf16_f32.
__device__ __forceinline__ unsigned int bfpack(float a, float b) {
  __hip_bfloat162 h = __float22bfloat162_rn(float2{a, b});
  union { __hip_bfloat162 h2; unsigned int u; } c;
  c.h2 = h;
  return c.u;
}

__launch_bounds__(256, 2)
__global__ void moe_grouped_gemm(const float* __restrict__ A,
                                 const float* __restrict__ W,
                                 float* __restrict__ C) {
  // bf16 tiles, double buffered. 2*(128*64 + 128*64)*2B = 64 KiB LDS.
  __shared__ ushort As[2][BM][BK];
  __shared__ ushort Bs[2][BN][BK];

  const int tid  = threadIdx.x;
  const int lane = tid & 63;
  const int wid  = tid >> 6;     // 4 waves
  const int wm   = wid >> 1;     // 0..1  (64-row half)
  const int wn   = wid & 1;      // 0..1  (64-col half)

  // XCD-aware remap: 8192 blocks; XCD x gets logical [x*1024, x*1024+1024)
  // => each XCD owns exactly one expert; n fastest => 4 consecutive blocks
  // share one A-panel (L2 reuse).
  const int b = blockIdx.x;
  const int L = (b & 7) * 1024 + (b >> 3);
  const int e  = L >> 10;        // expert
  const int t  = L & 1023;
  const int mt = t >> 2;         // 256 m-tiles
  const int nt = t & 3;          // 4 n-tiles

  const size_t mBase = (size_t)e * 32768 + (size_t)mt * BM;
  const int    nBase = nt * BN;

  const float* Ap = A + mBase * KDIM;
  const float* Wp = W + ((size_t)e * 512 + nBase) * KDIM;

  f32x4 acc[4][4];
  #pragma unroll
  for (int i = 0; i < 4; ++i)
    #pragma unroll
    for (int j = 0; j < 4; ++j)
      acc[i][j] = (f32x4){0.f, 0.f, 0.f, 0.f};

  // ---- prologue: stage K-tile 0 into buffer 0 ----
  {
    #pragma unroll
    for (int i = 0; i < 8; ++i) {
      const int idx = i * 256 + tid;
      const int row = idx >> 4;            // 16 threads per row
      const int col = (idx & 15) << 2;     // 4 floats each
      const float4 va = *(const float4*)(Ap + row * KDIM + col);
      const float4 vb = *(const float4*)(Wp + row * KDIM + col);
      const int sk = col ^ ((row & 7) << 3);   // T2 XOR swizzle (element idx)
      uint2 pa, pb;
      pa.x = bfpack(va.x, va.y); pa.y = bfpack(va.z, va.w);
      pb.x = bfpack(vb.x, vb.y); pb.y = bfpack(vb.z, vb.w);
      *(uint2*)&As[0][row][sk] = pa;
      *(uint2*)&Bs[0][row][sk] = pb;
    }
  }

  for (int kt = 0; kt < NT; ++kt) {
    __syncthreads();

    const bool pre = (kt + 1 < NT);
    float4 ra[8], rb[8];
    // ---- issue next tile's global loads early (hide HBM latency) ----
    if (pre) {
      const int k0 = (kt + 1) * BK;
      #pragma unroll
      for (int i = 0; i < 8; ++i) {
        const int idx = i * 256 + tid;
        const int row = idx >> 4;
        const int col = (idx & 15) << 2;
        ra[i] = *(const float4*)(Ap + row * KDIM + k0 + col);
        rb[i] = *(const float4*)(Wp + row * KDIM + k0 + col);
      }
    }

    // ---- compute current tile ----
    {
      const int buf = kt & 1;
      bf16x8 bf[4][2];
      #pragma unroll
      for (int ni = 0; ni < 4; ++ni) {
        const int rrow = wn * 64 + ni * 16 + (lane & 15);
        #pragma unroll
        for (int kk = 0; kk < 2; ++kk) {
          const int kc = (kk * 32 + (lane >> 4) * 8) ^ ((rrow & 7) << 3);
          bf[ni][kk] = *(const bf16x8*)&Bs[buf][rrow][kc];
        }
      }
      #pragma unroll
      for (int mi = 0; mi < 4; ++mi) {
        const int arow = wm * 64 + mi * 16 + (lane & 15);
        bf16x8 af[2];
        #pragma unroll
        for (int kk = 0; kk < 2; ++kk) {
          const int kc = (kk * 32 + (lane >> 4) * 8) ^ ((arow & 7) << 3);
          af[kk] = *(const bf16x8*)&As[buf][arow][kc];
        }
        #pragma unroll
        for (int ni = 0; ni < 4; ++ni) {
          acc[mi][ni] = __builtin_amdgcn_mfma_f32_16x16x32_bf16(af[0], bf[ni][0], acc[mi][ni], 0, 0, 0);
          acc[mi][ni] = __builtin_amdgcn_mfma_f32_16x16x32_bf16(af[1], bf[ni][1], acc[mi][ni], 0, 0, 0);
        }
      }
    }

    // ---- convert + write next tile into the other buffer ----
    if (pre) {
      const int nb = (kt + 1) & 1;
      #pragma unroll
      for (int i = 0; i < 8; ++i) {
        const int idx = i * 256 + tid;
        const int row = idx >> 4;
        const int col = (idx & 15) << 2;
        const int sk = col ^ ((row & 7) << 3);
        uint2 pa, pb;
        pa.x = bfpack(ra[i].x, ra[i].y); pa.y = bfpack(ra[i].z, ra[i].w);
        pb.x = bfpack(rb[i].x, rb[i].y); pb.y = bfpack(rb[i].z, rb[i].w);
        *(uint2*)&As[nb][row][sk] = pa;
        *(uint2*)&Bs[nb][row][sk] = pb;
      }
    }
  }

  // ---- epilogue: C[m][n], row = (lane>>4)*4 + reg, col = lane&15 ----
  #pragma unroll
  for (int mi = 0; mi < 4; ++mi) {
    #pragma unroll
    for (int reg = 0; reg < 4; ++reg) {
      const int r = wm * 64 + mi * 16 + ((lane >> 4) << 2) + reg;
      float* rowp = C + (mBase + r) * 512 + nBase + wn * 64 + (lane & 15);
      #pragma unroll
      for (int ni = 0; ni < 4; ++ni)
        rowp[ni * 16] = acc[mi][ni][reg];
    }
  }
}

extern "C" void kernel_launch(void* const* d_in, const int* in_sizes, int n_in,
                              void* d_out, int out_size, void* d_ws, size_t ws_size,
                              hipStream_t stream) {
  const float* inputs = (const float*)d_in[0];   // [262144, 512] fp32
  const float* weight = (const float*)d_in[1];   // [8, 512, 512] fp32
  float* out = (float*)d_out;                    // [262144, 512] fp32
  (void)d_ws; (void)ws_size; (void)in_sizes; (void)n_in;

  moe_grouped_gemm<<<8192, 256, 0, stream>>>(inputs, weight, out);
}

// Round 2
// 309.274 us; speedup vs baseline: 1.2929x; 1.2929x over previous
//
#include <hip/hip_runtime.h>
#include <hip/hip_bf16.h>

typedef __attribute__((ext_vector_type(4))) float f32x4;
typedef __attribute__((ext_vector_type(8))) short bf16x8;

#define BM 128
#define BN 128
#define BK 32
#define KDIM 512
#define NT (KDIM / BK)   // 16 K-tiles

// fp32 -> packed 2x bf16 (RNE). Compiler emits v_cvt_pk_bf16_f32.
__device__ __forceinline__ unsigned int bfpack(float a, float b) {
  __hip_bfloat162 h = __float22bfloat162_rn(float2{a, b});
  union { __hip_bfloat162 h2; unsigned int u; } c;
  c.h2 = h;
  return c.u;
}

__launch_bounds__(256, 3)
__global__ void moe_grouped_gemm(const float* __restrict__ A,
                                 const float* __restrict__ W,
                                 float* __restrict__ C) {
  // bf16 tiles, double buffered. 2*(128*32 + 128*32)*2B = 32 KiB LDS.
  // BK=32: 16 rows x 64B tile exactly fills the 32 banks for both the
  // ds_read_b128 fragment pattern and the uint2 staging writes -> no
  // swizzle needed, zero extra bank-conflict cycles.
  __shared__ ushort As[2][BM][BK];
  __shared__ ushort Bs[2][BN][BK];

  const int tid  = threadIdx.x;
  const int lane = tid & 63;
  const int wid  = tid >> 6;     // 4 waves
  const int wm   = wid >> 1;     // 0..1  (64-row half)
  const int wn   = wid & 1;      // 0..1  (64-col half)

  // XCD-aware remap: 8192 blocks; XCD x gets logical [x*1024, x*1024+1024)
  // => each XCD owns exactly one expert; n fastest => 4 consecutive blocks
  // share one A-panel (L2 reuse).
  const int b = blockIdx.x;
  const int L = (b & 7) * 1024 + (b >> 3);
  const int e  = L >> 10;        // expert
  const int t  = L & 1023;
  const int mt = t >> 2;         // 256 m-tiles
  const int nt = t & 3;          // 4 n-tiles

  const size_t mBase = (size_t)e * 32768 + (size_t)mt * BM;
  const int    nBase = nt * BN;

  const float* Ap = A + mBase * KDIM;
  const float* Wp = W + ((size_t)e * 512 + nBase) * KDIM;

  // staging geometry: 128x32 floats / 256 threads = 4 float4 per thread
  const int srow = tid >> 3;            // 8 threads per row (32 floats)
  const int scol = (tid & 7) << 2;      // 4 floats each

  f32x4 acc[4][4];
  #pragma unroll
  for (int i = 0; i < 4; ++i)
    #pragma unroll
    for (int j = 0; j < 4; ++j)
      acc[i][j] = (f32x4){0.f, 0.f, 0.f, 0.f};

  // ---- prologue: stage K-tile 0 into buffer 0 ----
  {
    #pragma unroll
    for (int i = 0; i < 4; ++i) {
      const int row = srow + i * 32;
      const float4 va = *(const float4*)(Ap + row * KDIM + scol);
      const float4 vb = *(const float4*)(Wp + row * KDIM + scol);
      uint2 pa, pb;
      pa.x = bfpack(va.x, va.y); pa.y = bfpack(va.z, va.w);
      pb.x = bfpack(vb.x, vb.y); pb.y = bfpack(vb.z, vb.w);
      *(uint2*)&As[0][row][scol] = pa;
      *(uint2*)&Bs[0][row][scol] = pb;
    }
  }

  for (int kt = 0; kt < NT; ++kt) {
    __syncthreads();

    const bool pre = (kt + 1 < NT);
    float4 ra[4], rb[4];
    // ---- phase 1: issue next tile's global loads (latency hides under MFMA) ----
    if (pre) {
      const int k0 = (kt + 1) * BK;
      #pragma unroll
      for (int i = 0; i < 4; ++i) {
        const int row = srow + i * 32;
        ra[i] = *(const float4*)(Ap + row * KDIM + k0 + scol);
        rb[i] = *(const float4*)(Wp + row * KDIM + k0 + scol);
      }
    }
    // keep the load issue above, and the vmcnt-waiting cvt uses below, the MFMA phase
    __builtin_amdgcn_sched_barrier(0);

    // ---- phase 2: compute current tile ----
    {
      const int buf = kt & 1;
      const int kc = (lane >> 4) << 3;   // k-offset: 8 elements per lane-group
      bf16x8 bf[4], af[4];
      #pragma unroll
      for (int ni = 0; ni < 4; ++ni) {
        const int rrow = wn * 64 + ni * 16 + (lane & 15);
        bf[ni] = *(const bf16x8*)&Bs[buf][rrow][kc];
      }
      #pragma unroll
      for (int mi = 0; mi < 4; ++mi) {
        const int arow = wm * 64 + mi * 16 + (lane & 15);
        af[mi] = *(const bf16x8*)&As[buf][arow][kc];
      }
      #pragma unroll
      for (int mi = 0; mi < 4; ++mi)
        #pragma unroll
        for (int ni = 0; ni < 4; ++ni)
          acc[mi][ni] = __builtin_amdgcn_mfma_f32_16x16x32_bf16(af[mi], bf[ni], acc[mi][ni], 0, 0, 0);
    }
    __builtin_amdgcn_sched_barrier(0);

    // ---- phase 3: convert + write next tile into the other buffer ----
    if (pre) {
      const int nb = (kt + 1) & 1;
      #pragma unroll
      for (int i = 0; i < 4; ++i) {
        const int row = srow + i * 32;
        uint2 pa, pb;
        pa.x = bfpack(ra[i].x, ra[i].y); pa.y = bfpack(ra[i].z, ra[i].w);
        pb.x = bfpack(rb[i].x, rb[i].y); pb.y = bfpack(rb[i].z, rb[i].w);
        *(uint2*)&As[nb][row][scol] = pa;
        *(uint2*)&Bs[nb][row][scol] = pb;
      }
    }
  }

  // ---- epilogue: C[m][n], row = (lane>>4)*4 + reg, col = lane&15 ----
  // nontemporal: C is write-once, keep it out of L2/L3 so A/B panels stay.
  #pragma unroll
  for (int mi = 0; mi < 4; ++mi) {
    #pragma unroll
    for (int reg = 0; reg < 4; ++reg) {
      const int r = wm * 64 + mi * 16 + ((lane >> 4) << 2) + reg;
      float* rowp = C + (mBase + r) * 512 + nBase + wn * 64 + (lane & 15);
      #pragma unroll
      for (int ni = 0; ni < 4; ++ni)
        __builtin_nontemporal_store(acc[mi][ni][reg], rowp + ni * 16);
    }
  }
}

extern "C" void kernel_launch(void* const* d_in, const int* in_sizes, int n_in,
                              void* d_out, int out_size, void* d_ws, size_t ws_size,
                              hipStream_t stream) {
  const float* inputs = (const float*)d_in[0];   // [262144, 512] fp32
  const float* weight = (const float*)d_in[1];   // [8, 512, 512] fp32
  float* out = (float*)d_out;                    // [262144, 512] fp32
  (void)d_ws; (void)ws_size; (void)in_sizes; (void)n_in;

  moe_grouped_gemm<<<8192, 256, 0, stream>>>(inputs, weight, out);
}